// Round 5
// baseline (90.087 us; speedup 1.0000x reference)
//
#include <hip/hip_runtime.h>

#define NN 1024
#define DD 128

// artanh(z)/z with reference-style clipping (z >= 0)
__device__ __forceinline__ float artanh_ratio(float z) {
  z = fminf(z, 1.0f - 1e-7f);
  if (z < 1e-4f) return 1.0f + z * z * (1.0f / 3.0f);
  return 0.5f * logf((1.0f + z) / (1.0f - z)) / z;
}

// One fused kernel: grid 256 x block 256. Wave w owns output row
// row = blockIdx.x*4 + w. Lane l handles j = j0 + l per 64-j chunk
// (computing s_ij, |x_j|^2, x_j.w2 in one pass), then u_ij; V[d] is
// accumulated in registers (lane owns d = l and l+64) via shfl broadcast.
__global__ __launch_bounds__(256) void hypagg_fused(
    const float* __restrict__ x, const float* __restrict__ adj,
    const float* __restrict__ aw, const float* __restrict__ bptr,
    float* __restrict__ out) {
  __shared__ __align__(16) float xi_lds[4 * DD];  // this block's 4 rows
  __shared__ __align__(16) float w2_lds[DD];      // aw[128:256]
  const int t = threadIdx.x;
  const int w = t >> 6;
  const int l = t & 63;
  const int row = blockIdx.x * 4 + w;

  xi_lds[t] = x[blockIdx.x * 4 * DD + t];
  xi_lds[t + 256] = x[blockIdx.x * 4 * DD + t + 256];
  if (t < DD) w2_lds[t] = aw[DD + t];
  __syncthreads();

  const float attb = bptr[0];
  const float* xi = &xi_lds[w * DD];
  const float xi0 = xi[l];
  const float xi1 = xi[l + 64];

  // own-row scalars: |x_i|^2 and left_i = h_i * (x_i . w[:128])
  float ra = xi0 * xi0 + xi1 * xi1;
  float rb = xi0 * aw[l] + xi1 * aw[l + 64];
#pragma unroll
  for (int m = 1; m < 64; m <<= 1) {
    ra += __shfl_xor(ra, m, 64);
    rb += __shfl_xor(rb, m, 64);
  }
  const float nx2i = ra;
  const float beta = 1.0f - nx2i;                 // raw (num factor)
  const float betac = fmaxf(beta, 1e-15f);        // clipped (2/lam)
  const float hi = artanh_ratio(fmaxf(sqrtf(nx2i), 1e-15f));
  const float lfti = hi * rb;

  float V0 = 0.0f, V1 = 0.0f, SA = 0.0f;

  for (int j0 = 0; j0 < NN; j0 += 64) {
    const int jj = j0 + l;
    const float* xj = x + jj * DD;
    float s = 0.0f, ny2 = 0.0f, rj = 0.0f;
#pragma unroll 8
    for (int k4 = 0; k4 < DD / 4; ++k4) {
      const float4 b4 = *(const float4*)(xj + k4 * 4);
      const float4 a4 = *(const float4*)(xi + k4 * 4);
      const float4 w4 = *(const float4*)(&w2_lds[k4 * 4]);
      s   = fmaf(a4.x, b4.x, fmaf(a4.y, b4.y, fmaf(a4.z, b4.z, fmaf(a4.w, b4.w, s))));
      ny2 = fmaf(b4.x, b4.x, fmaf(b4.y, b4.y, fmaf(b4.z, b4.z, fmaf(b4.w, b4.w, ny2))));
      rj  = fmaf(w4.x, b4.x, fmaf(w4.y, b4.y, fmaf(w4.z, b4.z, fmaf(w4.w, b4.w, rj))));
    }
    // pair scalars (c = 1)
    const float hj = artanh_ratio(fmaxf(sqrtf(ny2), 1e-15f));
    const float rgtj = hj * rj;                       // right_j
    const float al = 1.0f - 2.0f * s + ny2;           // alpha_ij
    const float den = fmaxf(1.0f - 2.0f * s + nx2i * ny2, 1e-15f);
    float s2 = fmaxf(al * al * nx2i - 2.0f * al * beta * s + beta * beta * ny2, 0.0f);
    s2 = s2 / (den * den);                            // |sub|^2
    const float sn = fmaxf(sqrtf(s2), 1e-15f);
    const float G = betac * artanh_ratio(sn);
    const float sig = 1.0f / (1.0f + expf(-(lfti + rgtj + attb)));
    const float u = sig * adj[row * NN + jj] * G / den;
    SA = fmaf(u, al, SA);

    // V[d] += sum_j u_j * x_j[d] ; lane owns d = {l, l+64}
#pragma unroll 16
    for (int jq = 0; jq < 64; ++jq) {
      const float uq = __shfl(u, jq, 64);
      const float xd0 = x[(j0 + jq) * DD + l];
      const float xd1 = x[(j0 + jq) * DD + l + 64];
      V0 = fmaf(uq, xd0, V0);
      V1 = fmaf(uq, xd1, V1);
    }
  }

#pragma unroll
  for (int m = 1; m < 64; m <<= 1) SA += __shfl_xor(SA, m, 64);

  // support_t = beta*V - SA*x_i ; then expmap + proj
  const float u0 = beta * V0 - SA * xi0;
  const float u1 = beta * V1 - SA * xi1;
  float p0 = u0 * u0 + u1 * u1;    // -> |u|^2
  float p1 = xi0 * u0 + xi1 * u1;  // -> x.u
#pragma unroll
  for (int m = 1; m < 64; m <<= 1) {
    p0 += __shfl_xor(p0, m, 64);
    p1 += __shfl_xor(p1, m, 64);
  }
  const float un = fmaxf(sqrtf(p0), 1e-15f);
  const float lam = 2.0f / betac;
  const float tau = tanhf(0.5f * lam * un) / un;   // second = tau*u
  const float y2 = tau * tau * p0;                 // |second|^2
  const float xy = tau * p1;                       // x.second
  const float numx = 1.0f + 2.0f * xy + y2;
  const float dene = fmaxf(1.0f + 2.0f * xy + nx2i * y2, 1e-15f);
  float r0 = (numx * xi0 + beta * tau * u0) / dene;
  float r1 = (numx * xi1 + beta * tau * u1) / dene;
  const float n2 = numx * numx * nx2i + 2.0f * numx * beta * xy + beta * beta * y2;
  const float n = fmaxf(sqrtf(n2) / dene, 1e-15f);
  const float maxn = 1.0f - 4e-3f;  // (1-PROJ_EPS)/sqrt(c)
  if (n > maxn) {
    const float sc = maxn / n;
    r0 *= sc;
    r1 *= sc;
  }
  // Output dtype = float32 (reference returns f32) — store floats.
  out[row * DD + l] = r0;
  out[row * DD + l + 64] = r1;
}

extern "C" void kernel_launch(void* const* d_in, const int* in_sizes, int n_in,
                              void* d_out, int out_size, void* d_ws, size_t ws_size,
                              hipStream_t stream) {
  // Bind inputs BY SIZE (unique: x=131072, adj=1048576, att_w=256, att_b=1)
  // — robust to any harness input ordering.
  const float* x = nullptr;
  const float* adj = nullptr;
  const float* aw = nullptr;
  const float* ab = nullptr;
  for (int i = 0; i < n_in; ++i) {
    switch (in_sizes[i]) {
      case NN * DD:  x   = (const float*)d_in[i]; break;
      case NN * NN:  adj = (const float*)d_in[i]; break;
      case 2 * DD:   aw  = (const float*)d_in[i]; break;
      case 1:        ab  = (const float*)d_in[i]; break;
      default: break;
    }
  }
  float* out = (float*)d_out;
  hipLaunchKernelGGL(hypagg_fused, dim3(NN / 4), dim3(256), 0, stream,
                     x, adj, aw, ab, out);
}